// Round 2
// baseline (227.766 us; speedup 1.0000x reference)
//
#include <hip/hip_runtime.h>
#include <hip/hip_bf16.h>

// ChildSum Tree-LSTM, MI355X. B=32, N=511 (full binary heap, relabeled i -> N-1-i):
// children of node i are 2i-511, 2i-512; parent(i) = (i>>1)+256; sibling(i) = i^1.
// Level-parallel bf16-MFMA GEMMs, fp32 accum/state.
// v2: sibling-paired waves (R=2 row-tiles), hsum precomputed in previous level's
// epilogue (no bf16 repack in hot loop), shared acc_fx for both children,
// 4 waves/block on one m-tile so B-fragments hit L1.

#define NN 511
#define BB 32
#define DD 256

typedef __attribute__((ext_vector_type(8))) short short8;
typedef __attribute__((ext_vector_type(4))) float f32x4;

__device__ __forceinline__ short f2bf(float f) {
    union { float f; unsigned int u; } v; v.f = f;
    unsigned int r = (v.u + 0x7FFFu + ((v.u >> 16) & 1u)) >> 16;  // RNE
    return (short)(unsigned short)r;
}
__device__ __forceinline__ float sigmf(float x) { return 1.0f / (1.0f + __expf(-x)); }

// ---- ws layout (bytes) ----
#define OFF_XBF   0u            // [N][B][256] bf16  = 8,372,224
#define OFF_HBF   8372224u      // [N][B][256] bf16  = 8,372,224
#define OFF_HS    16744448u     // [255][B][256] bf16 = 4,177,920  (hsum of node p at p-256)
#define OFF_CBUF  20922368u     // [N][B][256] f32   = 16,744,448
#define OFF_WIOU  37666816u     // [768][512] bf16   = 786,432  (cols 0:256 Wx, 256:512 Wh)
#define OFF_WF    38453248u     // [256][512] bf16   = 262,144
#define OFF_BIOU  38715392u     // [768] f32
#define OFF_BF    38718464u     // [256] f32
// total ~38.7 MB

__global__ void prep_x(const float* __restrict__ inp, short* __restrict__ xbf) {
    int idx = blockIdx.x * 256 + threadIdx.x;
    if (idx >= NN * BB * DD) return;
    int n = idx / (BB * DD);
    int rem = idx % (BB * DD);
    int b = rem / DD;
    int c = rem % DD;
    xbf[idx] = f2bf(inp[((long)b * NN + n) * DD + c]);
}

__global__ void prep_w(const float* __restrict__ Wx, const float* __restrict__ Wh,
                       const float* __restrict__ Wfx, const float* __restrict__ Wfh,
                       const float* __restrict__ bix, const float* __restrict__ bih,
                       const float* __restrict__ bfx, const float* __restrict__ bfh,
                       short* __restrict__ wiou, short* __restrict__ wf,
                       float* __restrict__ biou, float* __restrict__ bfc) {
    int tid = blockIdx.x * 256 + threadIdx.x;
    if (tid < 768 * 512) {
        int o = tid >> 9, c = tid & 511;
        float v = (c < 256) ? Wx[o * 256 + c] : Wh[o * 256 + (c - 256)];
        wiou[tid] = f2bf(v);
    } else if (tid < 768 * 512 + 256 * 512) {
        int t = tid - 768 * 512;
        int mm = t >> 9, c = t & 511;
        float v = (c < 256) ? Wfx[mm * 256 + c] : Wfh[mm * 256 + (c - 256)];
        wf[t] = f2bf(v);
    } else if (tid < 768 * 512 + 256 * 512 + 768) {
        int o = tid - (768 * 512 + 256 * 512);
        biou[o] = bix[o] + bih[o];
    } else if (tid < 768 * 512 + 256 * 512 + 768 + 256) {
        int mm = tid - (768 * 512 + 256 * 512 + 768);
        bfc[mm] = bfx[mm] + bfh[mm];
    }
}

// Wave = sibling pair: gw = blockIdx.x*4+wid; j = gw>>1 (node pair), s = gw&1 (b-half).
// ri in {0,1}: node = istart + 2j + ri, b0 = s*16. blockIdx.y = m-tile (16 cols).
// MFMA 16x16x32 bf16: A[row=lane&15][k=(lane>>4)*8+j], D[row=(lane>>4)*4+r][col=lane&15].
template <bool LEAF>
__global__ __launch_bounds__(256) void level_v2(
    const short* __restrict__ xbf, short* __restrict__ hbf,
    short* __restrict__ hsbf, float* __restrict__ cbuf,
    const short* __restrict__ wiou, const short* __restrict__ wf,
    const float* __restrict__ biou, const float* __restrict__ bfc,
    float* __restrict__ out, int istart, int ncount) {
    const int lane = threadIdx.x & 63;
    const int wid = threadIdx.x >> 6;
    const int gw = blockIdx.x * 4 + wid;
    const int gw_total = ((ncount + 1) >> 1) << 1;
    if (gw >= gw_total) return;
    const int j = gw >> 1;
    const int s = gw & 1;
    const int b0 = s * 16;
    const bool valid1 = (2 * j + 1) < ncount;
    int nodes[2];
    nodes[0] = istart + 2 * j;
    nodes[1] = valid1 ? (nodes[0] + 1) : nodes[0];

    const int arow = lane & 15;   // A-row (batch) for A; out-col for B/D
    const int kgrp = lane >> 4;
    const int m = blockIdx.y * 16 + arow;

    // B bases (weight rows), k-chunk select by kgrp
    const short* Bi = wiou + (long)m * 512 + kgrp * 8;
    const short* Bo = wiou + (long)(256 + m) * 512 + kgrp * 8;
    const short* Bu = wiou + (long)(512 + m) * 512 + kgrp * 8;
    const short* Bf = wf + (long)m * 512 + kgrp * 8;

    // A bases per row-tile
    const short* Ax[2];
    const short* As[2];
    const short* A0[2];
    const short* A1[2];
#pragma unroll
    for (int ri = 0; ri < 2; ++ri) {
        const int node = nodes[ri];
        Ax[ri] = xbf + ((long)node * BB + b0 + arow) * DD + kgrp * 8;
        if (!LEAF) {
            As[ri] = hsbf + ((long)(node - 256) * BB + b0 + arow) * DD + kgrp * 8;
            A0[ri] = hbf + ((long)(2 * node - 511) * BB + b0 + arow) * DD + kgrp * 8;
            A1[ri] = hbf + ((long)(2 * node - 512) * BB + b0 + arow) * DD + kgrp * 8;
        }
    }

    f32x4 acc_i[2], acc_o[2], acc_u[2], acc_fx[2], acc_h0[2], acc_h1[2];
#pragma unroll
    for (int ri = 0; ri < 2; ++ri) {
        acc_i[ri] = (f32x4){0.f, 0.f, 0.f, 0.f};
        acc_o[ri] = (f32x4){0.f, 0.f, 0.f, 0.f};
        acc_u[ri] = (f32x4){0.f, 0.f, 0.f, 0.f};
        acc_fx[ri] = (f32x4){0.f, 0.f, 0.f, 0.f};
        acc_h0[ri] = (f32x4){0.f, 0.f, 0.f, 0.f};
        acc_h1[ri] = (f32x4){0.f, 0.f, 0.f, 0.f};
    }

    // x phase: K = 0..255
#pragma unroll
    for (int ks = 0; ks < 8; ++ks) {
        const int ko = ks * 32;
        short8 bi = *(const short8*)(Bi + ko);
        short8 bo = *(const short8*)(Bo + ko);
        short8 bu = *(const short8*)(Bu + ko);
        short8 bf;
        if (!LEAF) bf = *(const short8*)(Bf + ko);
#pragma unroll
        for (int ri = 0; ri < 2; ++ri) {
            short8 a = *(const short8*)(Ax[ri] + ko);
            acc_i[ri] = __builtin_amdgcn_mfma_f32_16x16x32_bf16(a, bi, acc_i[ri], 0, 0, 0);
            acc_o[ri] = __builtin_amdgcn_mfma_f32_16x16x32_bf16(a, bo, acc_o[ri], 0, 0, 0);
            acc_u[ri] = __builtin_amdgcn_mfma_f32_16x16x32_bf16(a, bu, acc_u[ri], 0, 0, 0);
            if (!LEAF)
                acc_fx[ri] = __builtin_amdgcn_mfma_f32_16x16x32_bf16(a, bf, acc_fx[ri], 0, 0, 0);
        }
    }

    if (!LEAF) {
        // h phase: K = 256..511 of concatenated weights; A = hsum / h0 / h1
#pragma unroll
        for (int ks = 0; ks < 8; ++ks) {
            const int ko = ks * 32;
            const int wko = 256 + ko;
            short8 bi = *(const short8*)(Bi + wko);
            short8 bo = *(const short8*)(Bo + wko);
            short8 bu = *(const short8*)(Bu + wko);
            short8 bf = *(const short8*)(Bf + wko);
#pragma unroll
            for (int ri = 0; ri < 2; ++ri) {
                short8 as = *(const short8*)(As[ri] + ko);
                short8 a0 = *(const short8*)(A0[ri] + ko);
                short8 a1 = *(const short8*)(A1[ri] + ko);
                acc_i[ri] = __builtin_amdgcn_mfma_f32_16x16x32_bf16(as, bi, acc_i[ri], 0, 0, 0);
                acc_o[ri] = __builtin_amdgcn_mfma_f32_16x16x32_bf16(as, bo, acc_o[ri], 0, 0, 0);
                acc_u[ri] = __builtin_amdgcn_mfma_f32_16x16x32_bf16(as, bu, acc_u[ri], 0, 0, 0);
                acc_h0[ri] = __builtin_amdgcn_mfma_f32_16x16x32_bf16(a0, bf, acc_h0[ri], 0, 0, 0);
                acc_h1[ri] = __builtin_amdgcn_mfma_f32_16x16x32_bf16(a1, bf, acc_h1[ri], 0, 0, 0);
            }
        }
    }

    // epilogue
    const float bi_v = biou[m];
    const float bo_v = biou[256 + m];
    const float bu_v = biou[512 + m];
    const float bf_v = LEAF ? 0.f : bfc[m];
    float hv[2][4];
#pragma unroll
    for (int ri = 0; ri < 2; ++ri) {
        const int node = nodes[ri];
#pragma unroll
        for (int r = 0; r < 4; ++r) {
            const int b = b0 + kgrp * 4 + r;
            const float iv = sigmf(acc_i[ri][r] + bi_v);
            const float ov = sigmf(acc_o[ri][r] + bo_v);
            const float uv = tanhf(acc_u[ri][r] + bu_v);
            float c;
            if (LEAF) {
                c = iv * uv;
            } else {
                const float f0 = sigmf(acc_fx[ri][r] + acc_h0[ri][r] + bf_v);
                const float f1 = sigmf(acc_fx[ri][r] + acc_h1[ri][r] + bf_v);
                const float cc0 = cbuf[((long)(2 * node - 511) * BB + b) * DD + m];
                const float cc1 = cbuf[((long)(2 * node - 512) * BB + b) * DD + m];
                c = iv * uv + f0 * cc0 + f1 * cc1;
            }
            const float h = ov * tanhf(c);
            hv[ri][r] = h;
            const long rowg = (long)node * BB + b;
            cbuf[rowg * DD + m] = c;
            hbf[rowg * DD + m] = f2bf(h);
            out[2 * BB * DD + ((long)b * NN + node) * DD + m] = h;  // hiddens[b][node][m]
            if (!LEAF && node == NN - 1) {
                out[b * DD + m] = c;                 // root_c
                out[BB * DD + b * DD + m] = h;       // root_h
            }
        }
    }
    // hsum for the parent (siblings nodes[0], nodes[1] live in this wave)
    if (valid1) {
        const int p = (nodes[0] >> 1) + 256;
#pragma unroll
        for (int r = 0; r < 4; ++r) {
            const int b = b0 + kgrp * 4 + r;
            hsbf[((long)(p - 256) * BB + b) * DD + m] = f2bf(hv[0][r] + hv[1][r]);
        }
    }
}

extern "C" void kernel_launch(void* const* d_in, const int* in_sizes, int n_in,
                              void* d_out, int out_size, void* d_ws, size_t ws_size,
                              hipStream_t stream) {
    (void)in_sizes; (void)n_in; (void)out_size; (void)ws_size;
    const float* inputs = (const float*)d_in[0];
    const float* W_ioux = (const float*)d_in[1];
    const float* b_ioux = (const float*)d_in[2];
    const float* W_iouh = (const float*)d_in[3];
    const float* b_iouh = (const float*)d_in[4];
    const float* W_fx = (const float*)d_in[5];
    const float* b_fx = (const float*)d_in[6];
    const float* W_fh = (const float*)d_in[7];
    const float* b_fh = (const float*)d_in[8];
    // d_in[9] children_idx unused: structure is the static full binary heap.

    char* ws = (char*)d_ws;
    short* xbf = (short*)(ws + OFF_XBF);
    short* hbf = (short*)(ws + OFF_HBF);
    short* hsbf = (short*)(ws + OFF_HS);
    float* cbuf = (float*)(ws + OFF_CBUF);
    short* wiou = (short*)(ws + OFF_WIOU);
    short* wf = (short*)(ws + OFF_WF);
    float* biou = (float*)(ws + OFF_BIOU);
    float* bfc = (float*)(ws + OFF_BF);
    float* out = (float*)d_out;

    prep_x<<<dim3((NN * BB * DD + 255) / 256), dim3(256), 0, stream>>>(inputs, xbf);
    prep_w<<<dim3((768 * 512 + 256 * 512 + 768 + 256 + 255) / 256), dim3(256), 0, stream>>>(
        W_ioux, W_iouh, W_fx, W_fh, b_ioux, b_iouh, b_fx, b_fh, wiou, wf, biou, bfc);

    // leaves: nodes [0,256)
    {
        const int ncount = 256;
        const int gw_total = ncount;               // sibling-pair waves
        level_v2<true><<<dim3((gw_total + 3) / 4, 16), dim3(256), 0, stream>>>(
            xbf, hbf, hsbf, cbuf, wiou, wf, biou, bfc, out, 0, ncount);
    }
    // internal levels d = 7 (128 nodes) .. d = 0 (root)
    for (int d = 7; d >= 0; --d) {
        const int istart = 512 - (1 << (d + 1));
        const int ncount = 1 << d;
        const int gw_total = ((ncount + 1) >> 1) << 1;
        level_v2<false><<<dim3((gw_total + 3) / 4, 16), dim3(256), 0, stream>>>(
            xbf, hbf, hsbf, cbuf, wiou, wf, biou, bfc, out, istart, ncount);
    }
}

// Round 3
// 227.751 us; speedup vs baseline: 1.0001x; 1.0001x over previous
//
#include <hip/hip_runtime.h>
#include <hip/hip_bf16.h>

// ChildSum Tree-LSTM, MI355X. B=32, N=511 (full binary heap, relabeled i -> N-1-i):
// children of node i are 2i-511, 2i-512; parent(i) = (i>>1)+256; sibling(i) = i^1.
// Level-parallel bf16-MFMA GEMMs, fp32 accum/state.
// v2: sibling-paired waves (R=2 row-tiles), hsum precomputed in previous level's
// epilogue (no bf16 repack in hot loop), shared acc_fx for both children,
// 4 waves/block on one m-tile so B-fragments hit L1.

#define NN 511
#define BB 32
#define DD 256

typedef __attribute__((ext_vector_type(8))) short short8;
typedef __attribute__((ext_vector_type(4))) float f32x4;

__device__ __forceinline__ short f2bf(float f) {
    union { float f; unsigned int u; } v; v.f = f;
    unsigned int r = (v.u + 0x7FFFu + ((v.u >> 16) & 1u)) >> 16;  // RNE
    return (short)(unsigned short)r;
}
__device__ __forceinline__ float sigmf(float x) { return 1.0f / (1.0f + __expf(-x)); }

// ---- ws layout (bytes) ----
#define OFF_XBF   0u            // [N][B][256] bf16  = 8,372,224
#define OFF_HBF   8372224u      // [N][B][256] bf16  = 8,372,224
#define OFF_HS    16744448u     // [255][B][256] bf16 = 4,177,920  (hsum of node p at p-256)
#define OFF_CBUF  20922368u     // [N][B][256] f32   = 16,744,448
#define OFF_WIOU  37666816u     // [768][512] bf16   = 786,432  (cols 0:256 Wx, 256:512 Wh)
#define OFF_WF    38453248u     // [256][512] bf16   = 262,144
#define OFF_BIOU  38715392u     // [768] f32
#define OFF_BF    38718464u     // [256] f32
// total ~38.7 MB

__global__ void prep_x(const float* __restrict__ inp, short* __restrict__ xbf) {
    int idx = blockIdx.x * 256 + threadIdx.x;
    if (idx >= NN * BB * DD) return;
    int n = idx / (BB * DD);
    int rem = idx % (BB * DD);
    int b = rem / DD;
    int c = rem % DD;
    xbf[idx] = f2bf(inp[((long)b * NN + n) * DD + c]);
}

__global__ void prep_w(const float* __restrict__ Wx, const float* __restrict__ Wh,
                       const float* __restrict__ Wfx, const float* __restrict__ Wfh,
                       const float* __restrict__ bix, const float* __restrict__ bih,
                       const float* __restrict__ bfx, const float* __restrict__ bfh,
                       short* __restrict__ wiou, short* __restrict__ wf,
                       float* __restrict__ biou, float* __restrict__ bfc) {
    int tid = blockIdx.x * 256 + threadIdx.x;
    if (tid < 768 * 512) {
        int o = tid >> 9, c = tid & 511;
        float v = (c < 256) ? Wx[o * 256 + c] : Wh[o * 256 + (c - 256)];
        wiou[tid] = f2bf(v);
    } else if (tid < 768 * 512 + 256 * 512) {
        int t = tid - 768 * 512;
        int mm = t >> 9, c = t & 511;
        float v = (c < 256) ? Wfx[mm * 256 + c] : Wfh[mm * 256 + (c - 256)];
        wf[t] = f2bf(v);
    } else if (tid < 768 * 512 + 256 * 512 + 768) {
        int o = tid - (768 * 512 + 256 * 512);
        biou[o] = bix[o] + bih[o];
    } else if (tid < 768 * 512 + 256 * 512 + 768 + 256) {
        int mm = tid - (768 * 512 + 256 * 512 + 768);
        bfc[mm] = bfx[mm] + bfh[mm];
    }
}

// Wave = sibling pair: gw = blockIdx.x*4+wid; j = gw>>1 (node pair), s = gw&1 (b-half).
// ri in {0,1}: node = istart + 2j + ri, b0 = s*16. blockIdx.y = m-tile (16 cols).
// MFMA 16x16x32 bf16: A[row=lane&15][k=(lane>>4)*8+j], D[row=(lane>>4)*4+r][col=lane&15].
template <bool LEAF>
__global__ __launch_bounds__(256) void level_v2(
    const short* __restrict__ xbf, short* __restrict__ hbf,
    short* __restrict__ hsbf, float* __restrict__ cbuf,
    const short* __restrict__ wiou, const short* __restrict__ wf,
    const float* __restrict__ biou, const float* __restrict__ bfc,
    float* __restrict__ out, int istart, int ncount) {
    const int lane = threadIdx.x & 63;
    const int wid = threadIdx.x >> 6;
    const int gw = blockIdx.x * 4 + wid;
    const int gw_total = ((ncount + 1) >> 1) << 1;
    if (gw >= gw_total) return;
    const int j = gw >> 1;
    const int s = gw & 1;
    const int b0 = s * 16;
    const bool valid1 = (2 * j + 1) < ncount;
    int nodes[2];
    nodes[0] = istart + 2 * j;
    nodes[1] = valid1 ? (nodes[0] + 1) : nodes[0];

    const int arow = lane & 15;   // A-row (batch) for A; out-col for B/D
    const int kgrp = lane >> 4;
    const int m = blockIdx.y * 16 + arow;

    // B bases (weight rows), k-chunk select by kgrp
    const short* Bi = wiou + (long)m * 512 + kgrp * 8;
    const short* Bo = wiou + (long)(256 + m) * 512 + kgrp * 8;
    const short* Bu = wiou + (long)(512 + m) * 512 + kgrp * 8;
    const short* Bf = wf + (long)m * 512 + kgrp * 8;

    // A bases per row-tile
    const short* Ax[2];
    const short* As[2];
    const short* A0[2];
    const short* A1[2];
#pragma unroll
    for (int ri = 0; ri < 2; ++ri) {
        const int node = nodes[ri];
        Ax[ri] = xbf + ((long)node * BB + b0 + arow) * DD + kgrp * 8;
        if (!LEAF) {
            As[ri] = hsbf + ((long)(node - 256) * BB + b0 + arow) * DD + kgrp * 8;
            A0[ri] = hbf + ((long)(2 * node - 511) * BB + b0 + arow) * DD + kgrp * 8;
            A1[ri] = hbf + ((long)(2 * node - 512) * BB + b0 + arow) * DD + kgrp * 8;
        }
    }

    f32x4 acc_i[2], acc_o[2], acc_u[2], acc_fx[2], acc_h0[2], acc_h1[2];
#pragma unroll
    for (int ri = 0; ri < 2; ++ri) {
        acc_i[ri] = (f32x4){0.f, 0.f, 0.f, 0.f};
        acc_o[ri] = (f32x4){0.f, 0.f, 0.f, 0.f};
        acc_u[ri] = (f32x4){0.f, 0.f, 0.f, 0.f};
        acc_fx[ri] = (f32x4){0.f, 0.f, 0.f, 0.f};
        acc_h0[ri] = (f32x4){0.f, 0.f, 0.f, 0.f};
        acc_h1[ri] = (f32x4){0.f, 0.f, 0.f, 0.f};
    }

    // x phase: K = 0..255
#pragma unroll
    for (int ks = 0; ks < 8; ++ks) {
        const int ko = ks * 32;
        short8 bi = *(const short8*)(Bi + ko);
        short8 bo = *(const short8*)(Bo + ko);
        short8 bu = *(const short8*)(Bu + ko);
        short8 bf;
        if (!LEAF) bf = *(const short8*)(Bf + ko);
#pragma unroll
        for (int ri = 0; ri < 2; ++ri) {
            short8 a = *(const short8*)(Ax[ri] + ko);
            acc_i[ri] = __builtin_amdgcn_mfma_f32_16x16x32_bf16(a, bi, acc_i[ri], 0, 0, 0);
            acc_o[ri] = __builtin_amdgcn_mfma_f32_16x16x32_bf16(a, bo, acc_o[ri], 0, 0, 0);
            acc_u[ri] = __builtin_amdgcn_mfma_f32_16x16x32_bf16(a, bu, acc_u[ri], 0, 0, 0);
            if (!LEAF)
                acc_fx[ri] = __builtin_amdgcn_mfma_f32_16x16x32_bf16(a, bf, acc_fx[ri], 0, 0, 0);
        }
    }

    if (!LEAF) {
        // h phase: K = 256..511 of concatenated weights; A = hsum / h0 / h1
#pragma unroll
        for (int ks = 0; ks < 8; ++ks) {
            const int ko = ks * 32;
            const int wko = 256 + ko;
            short8 bi = *(const short8*)(Bi + wko);
            short8 bo = *(const short8*)(Bo + wko);
            short8 bu = *(const short8*)(Bu + wko);
            short8 bf = *(const short8*)(Bf + wko);
#pragma unroll
            for (int ri = 0; ri < 2; ++ri) {
                short8 as = *(const short8*)(As[ri] + ko);
                short8 a0 = *(const short8*)(A0[ri] + ko);
                short8 a1 = *(const short8*)(A1[ri] + ko);
                acc_i[ri] = __builtin_amdgcn_mfma_f32_16x16x32_bf16(as, bi, acc_i[ri], 0, 0, 0);
                acc_o[ri] = __builtin_amdgcn_mfma_f32_16x16x32_bf16(as, bo, acc_o[ri], 0, 0, 0);
                acc_u[ri] = __builtin_amdgcn_mfma_f32_16x16x32_bf16(as, bu, acc_u[ri], 0, 0, 0);
                acc_h0[ri] = __builtin_amdgcn_mfma_f32_16x16x32_bf16(a0, bf, acc_h0[ri], 0, 0, 0);
                acc_h1[ri] = __builtin_amdgcn_mfma_f32_16x16x32_bf16(a1, bf, acc_h1[ri], 0, 0, 0);
            }
        }
    }

    // epilogue
    const float bi_v = biou[m];
    const float bo_v = biou[256 + m];
    const float bu_v = biou[512 + m];
    const float bf_v = LEAF ? 0.f : bfc[m];
    float hv[2][4];
#pragma unroll
    for (int ri = 0; ri < 2; ++ri) {
        const int node = nodes[ri];
#pragma unroll
        for (int r = 0; r < 4; ++r) {
            const int b = b0 + kgrp * 4 + r;
            const float iv = sigmf(acc_i[ri][r] + bi_v);
            const float ov = sigmf(acc_o[ri][r] + bo_v);
            const float uv = tanhf(acc_u[ri][r] + bu_v);
            float c;
            if (LEAF) {
                c = iv * uv;
            } else {
                const float f0 = sigmf(acc_fx[ri][r] + acc_h0[ri][r] + bf_v);
                const float f1 = sigmf(acc_fx[ri][r] + acc_h1[ri][r] + bf_v);
                const float cc0 = cbuf[((long)(2 * node - 511) * BB + b) * DD + m];
                const float cc1 = cbuf[((long)(2 * node - 512) * BB + b) * DD + m];
                c = iv * uv + f0 * cc0 + f1 * cc1;
            }
            const float h = ov * tanhf(c);
            hv[ri][r] = h;
            const long rowg = (long)node * BB + b;
            cbuf[rowg * DD + m] = c;
            hbf[rowg * DD + m] = f2bf(h);
            out[2 * BB * DD + ((long)b * NN + node) * DD + m] = h;  // hiddens[b][node][m]
            if (!LEAF && node == NN - 1) {
                out[b * DD + m] = c;                 // root_c
                out[BB * DD + b * DD + m] = h;       // root_h
            }
        }
    }
    // hsum for the parent (siblings nodes[0], nodes[1] live in this wave)
    if (valid1) {
        const int p = (nodes[0] >> 1) + 256;
#pragma unroll
        for (int r = 0; r < 4; ++r) {
            const int b = b0 + kgrp * 4 + r;
            hsbf[((long)(p - 256) * BB + b) * DD + m] = f2bf(hv[0][r] + hv[1][r]);
        }
    }
}

extern "C" void kernel_launch(void* const* d_in, const int* in_sizes, int n_in,
                              void* d_out, int out_size, void* d_ws, size_t ws_size,
                              hipStream_t stream) {
    (void)in_sizes; (void)n_in; (void)out_size; (void)ws_size;
    const float* inputs = (const float*)d_in[0];
    const float* W_ioux = (const float*)d_in[1];
    const float* b_ioux = (const float*)d_in[2];
    const float* W_iouh = (const float*)d_in[3];
    const float* b_iouh = (const float*)d_in[4];
    const float* W_fx = (const float*)d_in[5];
    const float* b_fx = (const float*)d_in[6];
    const float* W_fh = (const float*)d_in[7];
    const float* b_fh = (const float*)d_in[8];
    // d_in[9] children_idx unused: structure is the static full binary heap.

    char* ws = (char*)d_ws;
    short* xbf = (short*)(ws + OFF_XBF);
    short* hbf = (short*)(ws + OFF_HBF);
    short* hsbf = (short*)(ws + OFF_HS);
    float* cbuf = (float*)(ws + OFF_CBUF);
    short* wiou = (short*)(ws + OFF_WIOU);
    short* wf = (short*)(ws + OFF_WF);
    float* biou = (float*)(ws + OFF_BIOU);
    float* bfc = (float*)(ws + OFF_BF);
    float* out = (float*)d_out;

    prep_x<<<dim3((NN * BB * DD + 255) / 256), dim3(256), 0, stream>>>(inputs, xbf);
    prep_w<<<dim3((768 * 512 + 256 * 512 + 768 + 256 + 255) / 256), dim3(256), 0, stream>>>(
        W_ioux, W_iouh, W_fx, W_fh, b_ioux, b_iouh, b_fx, b_fh, wiou, wf, biou, bfc);

    // leaves: nodes [0,256)
    {
        const int ncount = 256;
        const int gw_total = ncount;               // sibling-pair waves
        level_v2<true><<<dim3((gw_total + 3) / 4, 16), dim3(256), 0, stream>>>(
            xbf, hbf, hsbf, cbuf, wiou, wf, biou, bfc, out, 0, ncount);
    }
    // internal levels d = 7 (128 nodes) .. d = 0 (root)
    for (int d = 7; d >= 0; --d) {
        const int istart = 512 - (1 << (d + 1));
        const int ncount = 1 << d;
        const int gw_total = ((ncount + 1) >> 1) << 1;
        level_v2<false><<<dim3((gw_total + 3) / 4, 16), dim3(256), 0, stream>>>(
            xbf, hbf, hsbf, cbuf, wiou, wf, biou, bfc, out, istart, ncount);
    }
}